// Round 17
// baseline (46.788 us; speedup 1.0000x reference)
//
#include <hip/hip_runtime.h>
#include <hip/hip_bf16.h>

// Outer_14173392076867 — 2-kernel pipeline v16, MI355X gfx950.
// Occupancy via GRID (v14/v15 lesson: capacity without blocks is vacuous):
// grid = 1024 (8 q per block) x 38.4 KB LDS -> exactly 4 blocks/CU resident,
// 32 waves/CU (2x v12). Lean v10 wave structure (52 VGPR measured in v11,
// <= 64 -> 8 waves/SIMD). Phase-B A-frags half-empty (8 n rows, zero-guard);
// phase-B MFMA count doubles but is ~1 us chip-wide.
// K2: reduce 32 partials + bias + silu + fc2 -> out[256]

typedef __attribute__((ext_vector_type(8))) short short8;
typedef __attribute__((ext_vector_type(4))) float f32x4;

#define PADW 72      // LDS row pad (ushorts): 144B rows, 16B aligned
#define PADM 1032    // att row: 1024 + 8 ushorts -> 2064B rows
#define KTOT 32768L

__device__ __forceinline__ unsigned short f2b(float x) {
  union { float f; unsigned int u; } v; v.f = x;
  return (unsigned short)((v.u + 0x7FFFu + ((v.u >> 16) & 1u)) >> 16);
}

// packed f32x2 -> bf16x2 (RNE), single v_cvt_pk_bf16_f32; direct dword store
// only (v7-proven pattern).
__device__ __forceinline__ unsigned int pk_bf16(float a, float b) {
  unsigned int r;
  asm("v_cvt_pk_bf16_f32 %0, %1, %2" : "=v"(r) : "v"(a), "v"(b));
  return r;
}

// ---------------- K1: fused dX -> att (LDS) -> fc1 partial ----------------
// grid = 1024. XCD swizzle: sl = ((blk>>8)<<3)|(blk&7) in 0..31 -> iq = sl&3,
// h = sl>>2; ng = (blk>>3)&31 (8 q's per block). block = 512 (8 waves).
// Phase A: 4 double-q iterations; wave w: qsub = w&1, dblk = w>>1 (16-wide d).
// Phase B: wave w owns m-chunk 128; 8-row A-frags (c0<8 guard).
__global__ __launch_bounds__(512, 4)
void k_fused(const float* __restrict__ X, const float* __restrict__ Wl_g,
             const float* __restrict__ Wr_g,
             const float* __restrict__ fc1w,
             float* __restrict__ partial) {
  __shared__ float xs[8][3][64];                               //  6144 B
  __shared__ __align__(16) unsigned short dxs[2][3][16][PADW]; // 13824 B
  __shared__ __align__(16) union {
    struct {
      unsigned short wl[64][PADW];                             //  9216 B
      unsigned short wr[64][PADW];                             //  9216 B
    } w;                                                       // dead after frag build
    unsigned short att[8][PADM];                               // 16512 B
    float red[8][8][64];                                       // 16384 B
  } s;                                                         // => total 38400 B

  const int blk  = blockIdx.x;
  const int sl   = ((blk >> 8) << 3) | (blk & 7);  // slice (h,iq) in 0..31
  const int iq   = sl & 3;
  const int h    = sl >> 2;
  const int ng   = (blk >> 3) & 31;                // 8-q group
  const int tid  = threadIdx.x;
  const int lane = tid & 63;
  const int w    = tid >> 6;
  const int c0   = lane & 15;
  const int ks   = lane >> 4;
  const int qsub = w & 1;
  const int dblk = w >> 1;

  // ---- W slices (per h): coalesced f32 read, transposed bf16 store [d][j]
  const float* wlg = Wl_g + h * 4096;
  const float* wrg = Wr_g + h * 4096;
#pragma unroll
  for (int r = 0; r < 8; ++r) {
    int e = tid + r * 512;
    int j = e >> 6, d = e & 63;
    s.w.wl[d][j] = f2b(wlg[e]);
    s.w.wr[d][j] = f2b(wrg[e]);
  }
  // ---- X stage: 8 q's ([q][t][i], 1536 floats, coalesced), staged once
  const long xbase = ((long)(ng * 8) * 8 + h) * 192;
#pragma unroll
  for (int r = 0; r < 3; ++r) {
    int e = tid + r * 512;
    int q = e / 192;
    int rem = e - q * 192;
    xs[q][rem % 3][rem / 3] = X[xbase + (long)q * 1536 + rem];
  }
  __syncthreads();

  // ---- B fragments for the att GEMM (this wave's 16-wide d block)
  short8 bl[2], br[2];
#pragma unroll
  for (int kb = 0; kb < 2; ++kb) {
    const int d = dblk * 16 + c0;
    const int j0 = ks * 8 + 32 * kb;
    bl[kb] = *(const short8*)&s.w.wl[d][j0];
    br[kb] = *(const short8*)&s.w.wr[d][j0];
  }
  __syncthreads();                   // wl/wr dead; att region may be written

  const int dq = tid >> 8;           // dX sub-buffer this thread fills (0/1)
  const int il = (tid >> 4) & 15;    // dX row (local, 0..15)
  const int j4 = (tid & 15) << 2;    // 4-col chunk

  for (int it = 0; it < 4; ++it) {
    const int qd = it * 2 + dq;      // q this thread computes dX for
    // dX[i = iq*16+il][j], 3 t's, 4 j's per thread
#pragma unroll
    for (int t = 0; t < 3; ++t) {
      const float* xrow = &xs[qd][t][0];
      const float xi = xrow[iq * 16 + il];
      float d0 = xi - xrow[j4];
      float d1 = xi - xrow[j4 + 1];
      float d2 = xi - xrow[j4 + 2];
      float d3 = xi - xrow[j4 + 3];
      float s0 = d0 * d0 + 1e-5f, s1 = d1 * d1 + 1e-5f;
      float s2 = d2 * d2 + 1e-5f, s3 = d3 * d3 + 1e-5f;
      float i0 = __builtin_amdgcn_rsqf(s0), i1 = __builtin_amdgcn_rsqf(s1);
      float i2 = __builtin_amdgcn_rsqf(s2), i3 = __builtin_amdgcn_rsqf(s3);
      float e0 = __builtin_amdgcn_exp2f(-1.44269504f * (s0 * i0));
      float e1 = __builtin_amdgcn_exp2f(-1.44269504f * (s1 * i1));
      float e2 = __builtin_amdgcn_exp2f(-1.44269504f * (s2 * i2));
      float e3 = __builtin_amdgcn_exp2f(-1.44269504f * (s3 * i3));
      *(unsigned int*)&dxs[dq][t][il][j4] =
          pk_bf16(d0 * i0 * e0, d1 * i1 * e1);
      *(unsigned int*)&dxs[dq][t][il][j4 + 2] =
          pk_bf16(d2 * i2 * e2, d3 * i3 * e3);
    }
    __syncthreads();                 // dxs ready

    // att tile for q = it*2 + qsub: wave computes [16 i x 16 d], K=64 over j
    const int q = it * 2 + qsub;
    f32x4 acc;
    acc[0] = 0.f; acc[1] = 0.f; acc[2] = 0.f; acc[3] = 0.f;
#pragma unroll
    for (int t = 0; t < 3; ++t) {
      short8 a0 = *(const short8*)&dxs[qsub][t][c0][ks * 8];
      short8 a1 = *(const short8*)&dxs[qsub][t][c0][ks * 8 + 32];
      f32x4 xl; xl[0]=0.f; xl[1]=0.f; xl[2]=0.f; xl[3]=0.f;
      f32x4 xr; xr[0]=0.f; xr[1]=0.f; xr[2]=0.f; xr[3]=0.f;
      xl = __builtin_amdgcn_mfma_f32_16x16x32_bf16(a0, bl[0], xl, 0, 0, 0);
      xl = __builtin_amdgcn_mfma_f32_16x16x32_bf16(a1, bl[1], xl, 0, 0, 0);
      xr = __builtin_amdgcn_mfma_f32_16x16x32_bf16(a0, br[0], xr, 0, 0, 0);
      xr = __builtin_amdgcn_mfma_f32_16x16x32_bf16(a1, br[1], xr, 0, 0, 0);
      acc += xl * xr;
    }
    // store: m-local = i_local*64 + d = (ks*4+r)*64 + dblk*16 + c0
#pragma unroll
    for (int r = 0; r < 4; ++r)
      s.att[q][(ks * 4 + r) * 64 + dblk * 16 + c0] = f2b(acc[r]);
    if (it < 3) __syncthreads();     // dxs consumed; next iter may overwrite
  }
  __syncthreads();                   // all att tiles visible

  // ---- Phase B: fc1 partial, C[8n x 64k], wave w owns m-chunk 128.
  f32x4 facc[4];
#pragma unroll
  for (int cb = 0; cb < 4; ++cb) {
    facc[cb][0] = 0.f; facc[cb][1] = 0.f; facc[cb][2] = 0.f; facc[cb][3] = 0.f;
  }
  short8 zero8;
#pragma unroll
  for (int e = 0; e < 8; ++e) zero8[e] = 0;
  const float* bpf =
      fc1w + (long)c0 * KTOT + h * 4096 + iq * 1024 + w * 128 + ks * 8;
  const unsigned short* ap = &s.att[0][0] + (c0 & 7) * PADM + w * 128 + ks * 8;
#pragma unroll
  for (int sx = 0; sx < 4; ++sx) {
    short8 a = (c0 < 8) ? *(const short8*)(ap + sx * 32) : zero8;
#pragma unroll
    for (int cb = 0; cb < 4; ++cb) {
      const float* src = bpf + (long)cb * 16 * KTOT + sx * 32;
      f32x4 v0 = *(const f32x4*)(src);
      f32x4 v1 = *(const f32x4*)(src + 4);
      union { unsigned short us[8]; short8 s8; } pw;
      pw.us[0] = f2b(v0[0]);
      pw.us[1] = f2b(v0[1]);
      pw.us[2] = f2b(v0[2]);
      pw.us[3] = f2b(v0[3]);
      pw.us[4] = f2b(v1[0]);
      pw.us[5] = f2b(v1[1]);
      pw.us[6] = f2b(v1[2]);
      pw.us[7] = f2b(v1[3]);
      facc[cb] = __builtin_amdgcn_mfma_f32_16x16x32_bf16(a, pw.s8, facc[cb], 0, 0, 0);
    }
  }
  __syncthreads();                   // att reads done; red overlays region
  // valid C rows: n = ks*4+r in 0..7 -> ks < 2
  if (ks < 2) {
#pragma unroll
    for (int cb = 0; cb < 4; ++cb)
#pragma unroll
      for (int r = 0; r < 4; ++r)
        s.red[w][ks * 4 + r][c0 + 16 * cb] = facc[cb][r];
  }
  __syncthreads();
  {
    int nl = tid >> 6, k = tid & 63;   // 512 threads = 8n x 64k
    float sum = 0.f;
#pragma unroll
    for (int ww = 0; ww < 8; ++ww) sum += s.red[ww][nl][k];
    partial[(((long)sl) * 256 + ng * 8 + nl) * 64 + k] = sum;
  }
}

// ---------------- K2: reduce 32 partials + bias + silu + fc2 ----------------
__global__ __launch_bounds__(256)
void k_fc2(const float* __restrict__ partial, const float* __restrict__ fc1_b,
           const float* __restrict__ fc2_w, const float* __restrict__ fc2_b,
           float* __restrict__ out) {
  const int tid = threadIdx.x;
  const int n = blockIdx.x * 4 + (tid >> 6);
  const int k = tid & 63;
  float s = fc1_b[k];
#pragma unroll
  for (int sp = 0; sp < 32; ++sp)
    s += partial[((long)sp * 256 + n) * 64 + k];
  float g = s / (1.f + __expf(-s));   // silu
  float v = g * fc2_w[k];
#pragma unroll
  for (int off = 32; off > 0; off >>= 1)
    v += __shfl_xor(v, off, 64);
  if (k == 0) out[n] = v + fc2_b[0];
}

extern "C" void kernel_launch(void* const* d_in, const int* in_sizes, int n_in,
                              void* d_out, int out_size, void* d_ws, size_t ws_size,
                              hipStream_t stream) {
  const float* X    = (const float*)d_in[0];
  const float* Wl   = (const float*)d_in[1];
  const float* Wr   = (const float*)d_in[2];
  const float* fc1w = (const float*)d_in[3];
  const float* fc1b = (const float*)d_in[4];
  const float* fc2w = (const float*)d_in[5];
  const float* fc2b = (const float*)d_in[6];
  float* out = (float*)d_out;

  float* partial = (float*)d_ws;                               // 2,097,152 B

  hipLaunchKernelGGL(k_fused, dim3(1024), dim3(512), 0, stream, X, Wl, Wr, fc1w, partial);
  hipLaunchKernelGGL(k_fc2,   dim3(64), dim3(256), 0, stream, partial, fc1b, fc2w, fc2b, out);
}

// Round 18
// 32.030 us; speedup vs baseline: 1.4608x; 1.4608x over previous
//
#include <hip/hip_runtime.h>
#include <hip/hip_bf16.h>

// Outer_14173392076867 — 2-kernel pipeline v17 (= v12 restored; empirical
// optimum of the session, 32.31 us), MI355X gfx950.
// K1: fused per-(iq,h,ng16). Phase A: dX computed PER-LANE directly into MFMA
//     A-fragments (registers) — no LDS staging, no per-iteration barriers.
//     Each wave owns 2 q's x full d=64. Phase B: fc1 partial, fc1_w streamed
//     f32 from L2 with in-register f2b conversion (union pack pattern).
// K2: reduce 32 partials + bias + silu + fc2 -> out[256]
//
// Session findings locked in:
//  - occupancy: 2 blocks/CU (grid 512 x 8 waves) is the max useful point;
//    v16 (more blocks) and v13/v15 (forced waves/EU) regress or are vacuous.
//  - launches cost ~1-2 us; in-kernel device-scope semaphores cost ~20 us.
//  - XCD swizzle for the w1 stream: null (kept, harmless).
//  - pk_bf16 inline-asm only as direct dword store; vector assembly of asm
//    results miscompiles (v6/v6b). f2b bit-twiddle for everything else.

typedef __attribute__((ext_vector_type(8))) short short8;
typedef __attribute__((ext_vector_type(4))) float f32x4;

#define PADW 72      // wl/wr row pad (ushorts): 144B rows
#define PADM 1032    // att row: 1024 + 8 ushorts -> 2064B rows
#define KTOT 32768L

__device__ __forceinline__ unsigned short f2b(float x) {
  union { float f; unsigned int u; } v; v.f = x;
  return (unsigned short)((v.u + 0x7FFFu + ((v.u >> 16) & 1u)) >> 16);
}

// dX element: delta/dist * exp(-dist), dist = sqrt(delta^2 + eps)
__device__ __forceinline__ unsigned short dxval(float xi, float xj) {
  float d = xi - xj;
  float s = d * d + 1e-5f;
  float iv = __builtin_amdgcn_rsqf(s);
  float e = __builtin_amdgcn_exp2f(-1.44269504f * (s * iv));
  return f2b(d * iv * e);
}

// ---------------- K1: fused dX(reg) -> att MFMA -> fc1 partial ----------------
// grid = 512. XCD swizzle: sl = ((blk>>7)<<3)|(blk&7) -> iq = sl&3, h = sl>>2;
// ng = (blk>>3)&15. block = 512 (8 waves), 2 blocks/CU.
// Phase A: wave w handles q = 2w, 2w+1; per (q,t) lane computes A-frags
//   a0: dX[iq*16+c0][ks*8+e], a1: dX[iq*16+c0][32+ks*8+e] -> 8 MFMA vs bl/br.
// Phase B: wave w owns m-chunk 128; 16-row A-frags from att_s.
__global__ __launch_bounds__(512, 4)
void k_fused(const float* __restrict__ X, const float* __restrict__ Wl_g,
             const float* __restrict__ Wr_g,
             const float* __restrict__ fc1w,
             float* __restrict__ partial) {
  __shared__ float xs[16][3][64];                              // 12288 B
  __shared__ __align__(16) unsigned short wl[64][PADW];        //  9216 B
  __shared__ __align__(16) unsigned short wr[64][PADW];        //  9216 B
  __shared__ __align__(16) union {
    unsigned short att[16][PADM];                              // 33024 B
    float red[8][16][64];                                      // 32768 B
  } s;                                                         // => 63744 B

  const int blk  = blockIdx.x;
  const int sl   = ((blk >> 7) << 3) | (blk & 7);  // slice (h,iq) in 0..31
  const int iq   = sl & 3;
  const int h    = sl >> 2;
  const int ng   = (blk >> 3) & 15;
  const int tid  = threadIdx.x;
  const int lane = tid & 63;
  const int w    = tid >> 6;
  const int c0   = lane & 15;
  const int ks   = lane >> 4;

  // ---- W slices (per h): coalesced f32 read, transposed bf16 store [d][j]
  const float* wlg = Wl_g + h * 4096;
  const float* wrg = Wr_g + h * 4096;
#pragma unroll
  for (int r = 0; r < 8; ++r) {
    int e = tid + r * 512;
    int j = e >> 6, d = e & 63;
    wl[d][j] = f2b(wlg[e]);
    wr[d][j] = f2b(wrg[e]);
  }
  // ---- X for 16 n: [q][t][i] (3072 floats, coalesced)
  {
    const long xbase = ((long)(ng * 16) * 8 + h) * 192;
#pragma unroll
    for (int r = 0; r < 6; ++r) {
      int e = tid + r * 512;
      int q = e / 192;
      int rem = e - q * 192;
      int i = rem / 3;
      int t = rem - i * 3;
      xs[q][t][i] = X[xbase + (long)q * 1536 + rem];
    }
  }
  __syncthreads();

  // ---- B fragments for the att GEMM: full d=64 (4 cb), t-invariant
  short8 bl[4][2], br[4][2];
#pragma unroll
  for (int cb = 0; cb < 4; ++cb)
#pragma unroll
    for (int kb = 0; kb < 2; ++kb) {
      const int d = cb * 16 + c0;
      const int j0 = ks * 8 + 32 * kb;
      bl[cb][kb] = *(const short8*)&wl[d][j0];
      br[cb][kb] = *(const short8*)&wr[d][j0];
    }

  // ---- Phase A: per wave, 2 q's; A-frags in registers, 1 barrier total
#pragma unroll
  for (int qq = 0; qq < 2; ++qq) {
    const int q = 2 * w + qq;
    f32x4 acc[4];
#pragma unroll
    for (int cb = 0; cb < 4; ++cb) {
      acc[cb][0] = 0.f; acc[cb][1] = 0.f; acc[cb][2] = 0.f; acc[cb][3] = 0.f;
    }
#pragma unroll
    for (int t = 0; t < 3; ++t) {
      const float* xrow = &xs[q][t][0];
      const float xi = xrow[iq * 16 + c0];
      f32x4 xa = *(const f32x4*)(xrow + ks * 8);
      f32x4 xb = *(const f32x4*)(xrow + ks * 8 + 4);
      f32x4 xc = *(const f32x4*)(xrow + ks * 8 + 32);
      f32x4 xd = *(const f32x4*)(xrow + ks * 8 + 36);
      union { unsigned short us[8]; short8 s8; } A0, A1;
#pragma unroll
      for (int e = 0; e < 4; ++e) {
        A0.us[e]     = dxval(xi, xa[e]);
        A0.us[4 + e] = dxval(xi, xb[e]);
        A1.us[e]     = dxval(xi, xc[e]);
        A1.us[4 + e] = dxval(xi, xd[e]);
      }
#pragma unroll
      for (int cb = 0; cb < 4; ++cb) {
        f32x4 xl; xl[0]=0.f; xl[1]=0.f; xl[2]=0.f; xl[3]=0.f;
        f32x4 xr; xr[0]=0.f; xr[1]=0.f; xr[2]=0.f; xr[3]=0.f;
        xl = __builtin_amdgcn_mfma_f32_16x16x32_bf16(A0.s8, bl[cb][0], xl, 0, 0, 0);
        xl = __builtin_amdgcn_mfma_f32_16x16x32_bf16(A1.s8, bl[cb][1], xl, 0, 0, 0);
        xr = __builtin_amdgcn_mfma_f32_16x16x32_bf16(A0.s8, br[cb][0], xr, 0, 0, 0);
        xr = __builtin_amdgcn_mfma_f32_16x16x32_bf16(A1.s8, br[cb][1], xr, 0, 0, 0);
        acc[cb] += xl * xr;
      }
    }
    // C store: i-local = ks*4+r, d = cb*16+c0; m-local = i_local*64 + d
#pragma unroll
    for (int cb = 0; cb < 4; ++cb)
#pragma unroll
      for (int r = 0; r < 4; ++r)
        s.att[q][(ks * 4 + r) * 64 + cb * 16 + c0] = f2b(acc[cb][r]);
  }
  __syncthreads();

  // ---- Phase B: fc1 partial, C[16n x 64k], wave w owns m-chunk 128.
  f32x4 facc[4];
#pragma unroll
  for (int cb = 0; cb < 4; ++cb) {
    facc[cb][0] = 0.f; facc[cb][1] = 0.f; facc[cb][2] = 0.f; facc[cb][3] = 0.f;
  }
  const float* bpf =
      fc1w + (long)c0 * KTOT + h * 4096 + iq * 1024 + w * 128 + ks * 8;
  const unsigned short* ap = &s.att[0][0] + c0 * PADM + w * 128 + ks * 8;
#pragma unroll
  for (int sx = 0; sx < 4; ++sx) {
    short8 a = *(const short8*)(ap + sx * 32);
#pragma unroll
    for (int cb = 0; cb < 4; ++cb) {
      const float* src = bpf + (long)cb * 16 * KTOT + sx * 32;
      f32x4 v0 = *(const f32x4*)(src);
      f32x4 v1 = *(const f32x4*)(src + 4);
      union { unsigned short us[8]; short8 s8; } pw;
      pw.us[0] = f2b(v0[0]);
      pw.us[1] = f2b(v0[1]);
      pw.us[2] = f2b(v0[2]);
      pw.us[3] = f2b(v0[3]);
      pw.us[4] = f2b(v1[0]);
      pw.us[5] = f2b(v1[1]);
      pw.us[6] = f2b(v1[2]);
      pw.us[7] = f2b(v1[3]);
      facc[cb] = __builtin_amdgcn_mfma_f32_16x16x32_bf16(a, pw.s8, facc[cb], 0, 0, 0);
    }
  }
  __syncthreads();                   // att reads done; red reuse
#pragma unroll
  for (int cb = 0; cb < 4; ++cb)
#pragma unroll
    for (int r = 0; r < 4; ++r)
      s.red[w][ks * 4 + r][c0 + 16 * cb] = facc[cb][r];
  __syncthreads();
#pragma unroll
  for (int rep = 0; rep < 2; ++rep) {
    int e = tid + rep * 512;
    int nl = e >> 6, k = e & 63;
    float sum = 0.f;
#pragma unroll
    for (int ww = 0; ww < 8; ++ww) sum += s.red[ww][nl][k];
    partial[(((long)h * 4 + iq) * 256 + ng * 16 + nl) * 64 + k] = sum;
  }
}

// ---------------- K2: reduce 32 partials + bias + silu + fc2 ----------------
__global__ __launch_bounds__(256)
void k_fc2(const float* __restrict__ partial, const float* __restrict__ fc1_b,
           const float* __restrict__ fc2_w, const float* __restrict__ fc2_b,
           float* __restrict__ out) {
  const int tid = threadIdx.x;
  const int n = blockIdx.x * 4 + (tid >> 6);
  const int k = tid & 63;
  float s = fc1_b[k];
#pragma unroll
  for (int sp = 0; sp < 32; ++sp)
    s += partial[((long)sp * 256 + n) * 64 + k];
  float g = s / (1.f + __expf(-s));   // silu
  float v = g * fc2_w[k];
#pragma unroll
  for (int off = 32; off > 0; off >>= 1)
    v += __shfl_xor(v, off, 64);
  if (k == 0) out[n] = v + fc2_b[0];
}

extern "C" void kernel_launch(void* const* d_in, const int* in_sizes, int n_in,
                              void* d_out, int out_size, void* d_ws, size_t ws_size,
                              hipStream_t stream) {
  const float* X    = (const float*)d_in[0];
  const float* Wl   = (const float*)d_in[1];
  const float* Wr   = (const float*)d_in[2];
  const float* fc1w = (const float*)d_in[3];
  const float* fc1b = (const float*)d_in[4];
  const float* fc2w = (const float*)d_in[5];
  const float* fc2b = (const float*)d_in[6];
  float* out = (float*)d_out;

  float* partial = (float*)d_ws;                               // 2,097,152 B

  hipLaunchKernelGGL(k_fused, dim3(512), dim3(512), 0, stream, X, Wl, Wr, fc1w, partial);
  hipLaunchKernelGGL(k_fc2,   dim3(64), dim3(256), 0, stream, partial, fc1b, fc2w, fc2b, out);
}